// Round 9
// baseline (117.362 us; speedup 1.0000x reference)
//
#include <hip/hip_runtime.h>
#include <math.h>

#define BB 128
#define NN 256
#define WW 64
#define DD 128
#define KK 20
#define LL (BB*WW)   // 8192

// ---------------- Kernel A: per-node means of xr (row n = data[:,n,:] flattened) ----------------
__global__ void k_mean(const float* __restrict__ data, double* __restrict__ mean) {
    int n = blockIdx.x;
    int t = threadIdx.x;                  // 256 threads
    double s = 0.0;
    for (int c = 0; c < LL / 256; ++c) {
        int l = t + c * 256;
        int b = l >> 6, w = l & 63;
        s += (double)data[(b * NN + n) * WW + w];
    }
    for (int off = 32; off; off >>= 1) s += __shfl_down(s, off);
    __shared__ double red[4];
    int lane = t & 63, wid = t >> 6;
    if (lane == 0) red[wid] = s;
    __syncthreads();
    if (t == 0) mean[n] = (red[0] + red[1] + red[2] + red[3]) / (double)LL;
}

// ---------------- Kernel B: emb stats: e_em_i, e_em_j, ||emb||^2 ----------------
__global__ void k_embstats(const float* __restrict__ emb,
                           const float* __restrict__ att_em_i,
                           const float* __restrict__ att_em_j,
                           float* __restrict__ eemi, float* __restrict__ eemj,
                           double* __restrict__ nrm2) {
    int n = blockIdx.x;
    int t = threadIdx.x;                  // 128 threads
    float e = emb[n * DD + t];
    float pi = e * att_em_i[t];
    float pj = e * att_em_j[t];
    double pn = (double)e * (double)e;
    for (int off = 32; off; off >>= 1) {
        pi += __shfl_down(pi, off);
        pj += __shfl_down(pj, off);
        pn += __shfl_down(pn, off);
    }
    __shared__ float ri[2], rj[2];
    __shared__ double rn[2];
    int lane = t & 63, wid = t >> 6;
    if (lane == 0) { ri[wid] = pi; rj[wid] = pj; rn[wid] = pn; }
    __syncthreads();
    if (t == 0) { eemi[n] = ri[0] + ri[1]; eemj[n] = rj[0] + rj[1]; nrm2[n] = rn[0] + rn[1]; }
}

// ---------------- Kernel C: split-K covariance, fp32 LDS + fp64 accumulate ------
// cov5 body (60 VGPR, 34.8 KB LDS -> 4 blocks/CU) with SPLIT as a runtime arg so the
// grid can be 1024 blocks (4/CU, 16 waves/CU). cov7 post-mortem: bottleneck was wave
// count (2 blocks/CU from a 512-block grid), not pipelining.
__global__ __launch_bounds__(256) void k_cov8(const float* __restrict__ data,
                                              double* __restrict__ covp, int bpc) {
    const int j0 = blockIdx.x * 64;
    const int i0 = blockIdx.y * 64;
    const int bz = blockIdx.z;
    const int t = threadIdx.x;
    const int ti = t >> 4, tj = t & 15;   // both 0..15

    __shared__ float As[64][68];          // pad 68: A-read conflict-free, B-read 2-way (free)
    __shared__ float Bs[64][68];

    const int b0 = bz * bpc;
    double acc[4][4] = {};

    #pragma unroll 1
    for (int cb = 0; cb < bpc; ++cb) {
        const int b = b0 + cb;
        // stage chunk: global -> short-lived regs -> LDS (regs dead before compute)
        #pragma unroll
        for (int e = 0; e < 4; ++e) {
            int idx = t + e * 256, row = idx >> 4, q = idx & 15;
            float4 va = ((const float4*)(data + ((size_t)b * NN + i0 + row) * WW))[q];
            float4 vb = ((const float4*)(data + ((size_t)b * NN + j0 + row) * WW))[q];
            *(float4*)&As[row][4 * q] = va;
            *(float4*)&Bs[row][4 * q] = vb;
        }
        __syncthreads();

        // compute: 16 k-quads, 64 fp64 FMAs each
        #pragma unroll 2
        for (int q = 0; q < 16; ++q) {
            double bd[4][4];
            #pragma unroll
            for (int c = 0; c < 4; ++c) {
                float4 bf = *(const float4*)&Bs[tj + 16 * c][4 * q];
                bd[c][0] = (double)bf.x; bd[c][1] = (double)bf.y;
                bd[c][2] = (double)bf.z; bd[c][3] = (double)bf.w;
            }
            #pragma unroll
            for (int r = 0; r < 4; ++r) {
                float4 af = *(const float4*)&As[ti + 16 * r][4 * q];
                double a0 = (double)af.x, a1 = (double)af.y;
                double a2 = (double)af.z, a3 = (double)af.w;
                #pragma unroll
                for (int c = 0; c < 4; ++c)
                    acc[r][c] += a0 * bd[c][0] + a1 * bd[c][1]
                               + a2 * bd[c][2] + a3 * bd[c][3];
            }
        }
        __syncthreads();
    }

    #pragma unroll
    for (int r = 0; r < 4; ++r)
        #pragma unroll
        for (int c = 0; c < 4; ++c)
            covp[((size_t)bz * NN + i0 + ti + 16 * r) * NN + j0 + tj + 16 * c] = acc[r][c];
}

// ---------------- Kernel C2: reduce split-K partials, subtract mean term ----------------
__global__ void k_cov_reduce(const double* __restrict__ covp,
                             const double* __restrict__ mean,
                             double* __restrict__ cov, int split) {
    int idx = blockIdx.x * 256 + threadIdx.x;   // 0..65535
    int i = idx >> 8, j = idx & 255;
    double s = 0.0;
    for (int z = 0; z < split; ++z) s += covp[((size_t)z * NN + i) * NN + j];
    s -= (double)LL * mean[i] * mean[j];
    cov[i * NN + j] = s;
}

// ---------------- Kernel D: sim -> fp32, rank-select top-20 (stable desc, jax tie rule) --------
__global__ void k_sim_topk(const float* __restrict__ emb,
                           const double* __restrict__ nrm2,
                           const double* __restrict__ cov,
                           int* __restrict__ topk) {
    int i = blockIdx.x;
    int t = threadIdx.x;                  // 256 threads; thread t owns column j = t
    __shared__ float embI[DD];
    __shared__ float sim[NN];

    if (t < DD) embI[t] = emb[i * DD + t];
    __syncthreads();

    const float4* er = (const float4*)(emb + (size_t)t * DD);
    double dot = 0.0;
    #pragma unroll 8
    for (int d4 = 0; d4 < DD / 4; ++d4) {
        float4 v = er[d4];
        dot += (double)embI[4 * d4 + 0] * (double)v.x
             + (double)embI[4 * d4 + 1] * (double)v.y
             + (double)embI[4 * d4 + 2] * (double)v.z
             + (double)embI[4 * d4 + 3] * (double)v.w;
    }
    double cosv = dot / (sqrt(nrm2[i]) * sqrt(nrm2[t]) + 1e-8);
    double stdi = sqrt(cov[i * NN + i] + 1e-8);
    double stdj = sqrt(cov[t * NN + t] + 1e-8);
    double corrv = cov[i * NN + t] / (stdi * stdj + 1e-8);
    sim[t] = (float)(0.7 * cosv + 0.3 * corrv);
    __syncthreads();

    // rank = # elements strictly ahead of mine in (value desc, index asc) order
    float my = sim[t];
    int cnt = 0;
    #pragma unroll 8
    for (int u = 0; u < NN; ++u) {
        float s = sim[u];                 // uniform addr -> LDS broadcast, conflict-free
        cnt += (s > my || (s == my && u < t)) ? 1 : 0;
    }
    if (cnt < KK) topk[i * KK + cnt] = t;
}

// ---------------- Kernel E: xl = x @ lin_W — 128x128 tile, 8x8 register tile, float4 LDS -------
__global__ __launch_bounds__(256) void k_xl2(const float* __restrict__ data,
                                             const float* __restrict__ linW,
                                             float* __restrict__ xl) {
    const int r0 = blockIdx.x * 128;
    const int t = threadIdx.x;            // 256 threads
    const int ti = t >> 4, tj = t & 15;
    __shared__ float Xs[128][68];         // rows x k, float4-padded
    __shared__ float Wt[DD][68];          // transposed W: Wt[col][k]

    #pragma unroll
    for (int e = 0; e < 8; ++e) {
        int idx = t + e * 256, row = idx >> 4, q = idx & 15;
        float4 v = ((const float4*)(data + (size_t)(r0 + row) * WW))[q];
        *(float4*)&Xs[row][4 * q] = v;
    }
    #pragma unroll
    for (int e = 0; e < 32; ++e) {
        int idx = t + e * 256;            // idx = k*128 + col
        int k = idx >> 7, col = idx & 127;
        Wt[col][k] = linW[idx];
    }
    __syncthreads();

    float acc[8][8] = {};                 // rows 8*ti+r, cols tj+16*c
    #pragma unroll
    for (int q = 0; q < 16; ++q) {
        float4 wb[8];
        #pragma unroll
        for (int c = 0; c < 8; ++c) wb[c] = *(const float4*)&Wt[tj + 16 * c][4 * q];
        #pragma unroll
        for (int r = 0; r < 8; ++r) {
            float4 xa = *(const float4*)&Xs[8 * ti + r][4 * q];
            #pragma unroll
            for (int c = 0; c < 8; ++c)
                acc[r][c] += xa.x * wb[c].x + xa.y * wb[c].y
                           + xa.z * wb[c].z + xa.w * wb[c].w;
        }
    }
    #pragma unroll
    for (int r = 0; r < 8; ++r)
        #pragma unroll
        for (int c = 0; c < 8; ++c)
            xl[(size_t)(r0 + 8 * ti + r) * DD + tj + 16 * c] = acc[r][c];
}

// ---------------- Kernel E2: sil/sjl = xl.att_{i,j} + eem (one wave per row) ----------------
__global__ void k_sij(const float* __restrict__ xl,
                      const float* __restrict__ att_i,
                      const float* __restrict__ att_j,
                      const float* __restrict__ eemi,
                      const float* __restrict__ eemj,
                      float* __restrict__ sil, float* __restrict__ sjl) {
    int t = threadIdx.x;                  // 256 threads = 4 waves, one row each
    int lane = t & 63, wv = t >> 6;
    int v = blockIdx.x * 4 + wv;
    float x0 = xl[(size_t)v * DD + lane];
    float x1 = xl[(size_t)v * DD + 64 + lane];
    float pi = x0 * att_i[lane] + x1 * att_i[64 + lane];
    float pj = x0 * att_j[lane] + x1 * att_j[64 + lane];
    #pragma unroll
    for (int off = 32; off; off >>= 1) { pi += __shfl_down(pi, off); pj += __shfl_down(pj, off); }
    if (lane == 0) {
        int i = v & (NN - 1);
        sil[v] = pi + eemi[i];
        sjl[v] = pj + eemj[i];
    }
}

// ---------------- Kernel F: fused attention v2 ----------------
__global__ __launch_bounds__(512) void k_attn2(
        const float* __restrict__ xl, const int* __restrict__ topk,
        const float* __restrict__ sil, const float* __restrict__ sjl,
        const float* __restrict__ gnn_bias,
        const float* __restrict__ bn1_g, const float* __restrict__ bn1_b,
        const float* __restrict__ bn2_g, const float* __restrict__ bn2_b,
        const float* __restrict__ emb,
        const float* __restrict__ outW, const float* __restrict__ outb,
        float* __restrict__ out) {
    const int h = blockIdx.x;             // node half: 0 or 1
    const int b = blockIdx.y;             // batch
    const int t = threadIdx.x;            // 512 threads = 8 waves
    const int lane = t & 63, wv = t >> 6;
    const int q = lane & 31, half = lane >> 5;

    __shared__ float xls[NN * DD];        // 128 KB: xl[b]
    __shared__ int2 jwS[128 * KK];        // 20 KB: packed (j, w) per local node

    {
        const float4* src = (const float4*)(xl + (size_t)b * NN * DD);
        float4* dst = (float4*)xls;
        #pragma unroll
        for (int e = 0; e < 16; ++e) dst[t + e * 512] = src[t + e * 512];
    }

    // pre-phase: per-node softmax, scalar per thread (nodes h*128 .. h*128+127)
    if (t < 128) {
        int i = h * 128 + t;
        float si = sil[b * NN + i];
        int jj[KK]; float aa[KK];
        float amax = -3.4e38f;
        #pragma unroll
        for (int k = 0; k < KK; ++k) {
            int j = topk[i * KK + k];
            jj[k] = j;
            float a = si + sjl[b * NN + j];
            a = a > 0.f ? a : 0.2f * a;   // leaky relu
            aa[k] = a;
            amax = fmaxf(amax, a);
        }
        float den = 0.f;
        #pragma unroll
        for (int k = 0; k < KK; ++k) { float e = expf(aa[k] - amax); aa[k] = e; den += e; }
        float r = 1.f / den;
        #pragma unroll
        for (int k = 0; k < KK; ++k)
            jwS[t * KK + k] = make_int2(jj[k], __float_as_int(aa[k] * r));
    }
    __syncthreads();

    const float rbnd = 1.0f / sqrtf(1.0f + 1e-5f);
    const float4 gb = ((const float4*)gnn_bias)[q];
    const float4 g1 = ((const float4*)bn1_g)[q];
    const float4 b1 = ((const float4*)bn1_b)[q];
    const float4 g2 = ((const float4*)bn2_g)[q];
    const float4 b2 = ((const float4*)bn2_b)[q];
    const float4 ow = ((const float4*)outW)[q];
    const float ob0 = outb[0];

    for (int n = 0; n < 8; ++n) {
        int il = wv * 16 + 2 * n + half;  // local node 0..127
        int i  = h * 128 + il;

        float ax = 0.f, ay = 0.f, az = 0.f, aw = 0.f;
        #pragma unroll
        for (int k = 0; k < KK; ++k) {
            int2 p = jwS[il * KK + k];
            float w = __int_as_float(p.y);
            float4 xv = *(const float4*)&xls[p.x * DD + 4 * q];
            ax += w * xv.x; ay += w * xv.y; az += w * xv.z; aw += w * xv.w;
        }

        float4 em = *(const float4*)&emb[(size_t)i * DD + 4 * q];
        float o0 = (ax + gb.x) * rbnd * g1.x + b1.x; o0 = fmaxf(o0, 0.f);
        float o1 = (ay + gb.y) * rbnd * g1.y + b1.y; o1 = fmaxf(o1, 0.f);
        float o2 = (az + gb.z) * rbnd * g1.z + b1.z; o2 = fmaxf(o2, 0.f);
        float o3 = (aw + gb.w) * rbnd * g1.w + b1.w; o3 = fmaxf(o3, 0.f);
        float h0 = o0 * em.x * rbnd * g2.x + b2.x; h0 = fmaxf(h0, 0.f);
        float h1 = o1 * em.y * rbnd * g2.y + b2.y; h1 = fmaxf(h1, 0.f);
        float h2 = o2 * em.z * rbnd * g2.z + b2.z; h2 = fmaxf(h2, 0.f);
        float h3 = o3 * em.w * rbnd * g2.w + b2.w; h3 = fmaxf(h3, 0.f);

        float p4 = h0 * ow.x + h1 * ow.y + h2 * ow.z + h3 * ow.w;
        #pragma unroll
        for (int off = 16; off; off >>= 1) p4 += __shfl_xor(p4, off);
        if (q == 0) out[b * NN + i] = p4 + ob0;
    }
}

extern "C" void kernel_launch(void* const* d_in, const int* in_sizes, int n_in,
                              void* d_out, int out_size, void* d_ws, size_t ws_size,
                              hipStream_t stream) {
    const float* data     = (const float*)d_in[0];
    // d_in[1] = org_edge_index (unused, as in reference)
    const float* emb      = (const float*)d_in[2];
    const float* linW     = (const float*)d_in[3];
    const float* att_i    = (const float*)d_in[4];
    const float* att_j    = (const float*)d_in[5];
    const float* att_em_i = (const float*)d_in[6];
    const float* att_em_j = (const float*)d_in[7];
    const float* gnn_bias = (const float*)d_in[8];
    const float* bn1_g    = (const float*)d_in[9];
    const float* bn1_b    = (const float*)d_in[10];
    const float* bn2_g    = (const float*)d_in[11];
    const float* bn2_b    = (const float*)d_in[12];
    const float* outW     = (const float*)d_in[13];
    const float* outb     = (const float*)d_in[14];
    float* out = (float*)d_out;

    char* ws = (char*)d_ws;
    double* mean  = (double*)(ws + 0);                       // 2 KB
    double* nrm2  = (double*)(ws + 2048);                    // 2 KB
    float*  eemi  = (float*)(ws + 4096);                     // 1 KB
    float*  eemj  = (float*)(ws + 5120);                     // 1 KB
    int*    topk  = (int*)(ws + 8192);                       // 20 KB
    double* cov   = (double*)(ws + 32768);                   // 512 KB
    // covp at +1MB: split*256*256*8 B (33.5 MB at split=64, 16.8 MB at split=32).
    // xl (16 MB) aliases covp (covp dead after k_cov_reduce, stream-ordered).
    double* covp  = (double*)(ws + (1 << 20));
    float*  xl    = (float*)(ws + (1 << 20));
    // sil/sjl reuse the cov region (cov dead after k_sim_topk).
    float*  sil   = (float*)(ws + 32768);
    float*  sjl   = (float*)(ws + 32768 + 131072);

    // pick split by available workspace (4 blocks/CU wants split=64)
    int split = (ws_size >= (size_t)(1 << 20) + (size_t)64 * NN * NN * 8 + (1 << 16)) ? 64 : 32;
    int bpc = BB / split;

    k_mean<<<NN, 256, 0, stream>>>(data, mean);
    k_embstats<<<NN, 128, 0, stream>>>(emb, att_em_i, att_em_j, eemi, eemj, nrm2);
    dim3 gc(NN / 64, NN / 64, split);
    k_cov8<<<gc, 256, 0, stream>>>(data, covp, bpc);
    k_cov_reduce<<<NN * NN / 256, 256, 0, stream>>>(covp, mean, cov, split);
    k_sim_topk<<<NN, 256, 0, stream>>>(emb, nrm2, cov, topk);
    k_xl2<<<(BB * NN) / 128, 256, 0, stream>>>(data, linW, xl);
    k_sij<<<(BB * NN) / 4, 256, 0, stream>>>(xl, att_i, att_j, eemi, eemj, sil, sjl);
    dim3 ga(2, BB);
    k_attn2<<<ga, 512, 0, stream>>>(xl, topk, sil, sjl, gnn_bias,
                                    bn1_g, bn1_b, bn2_g, bn2_b, emb, outW, outb, out);
}

// Round 10
// 107.334 us; speedup vs baseline: 1.0934x; 1.0934x over previous
//
#include <hip/hip_runtime.h>
#include <math.h>

#define BB 128
#define NN 256
#define WW 64
#define DD 128
#define KK 20
#define LL (BB*WW)   // 8192
#define NPAIR (NN*(NN+1)/2)   // 32896 upper-triangle pairs

// ---------------- Kernel A: fused per-node means (blocks 0..255) + emb stats (blocks 256..383) --
__global__ void k_pre(const float* __restrict__ data, const float* __restrict__ emb,
                      const float* __restrict__ att_em_i, const float* __restrict__ att_em_j,
                      double* __restrict__ mean, float* __restrict__ eemi,
                      float* __restrict__ eemj, double* __restrict__ nrm2) {
    const int t = threadIdx.x;            // 256 threads
    const int lane = t & 63, wid = t >> 6;
    if (blockIdx.x < NN) {
        // ---- mean of row n of xr ----
        int n = blockIdx.x;
        double s = 0.0;
        for (int c = 0; c < LL / 256; ++c) {
            int l = t + c * 256;
            int b = l >> 6, w = l & 63;
            s += (double)data[(b * NN + n) * WW + w];
        }
        for (int off = 32; off; off >>= 1) s += __shfl_down(s, off);
        __shared__ double redm[4];
        if (lane == 0) redm[wid] = s;
        __syncthreads();
        if (t == 0) mean[n] = (redm[0] + redm[1] + redm[2] + redm[3]) / (double)LL;
    } else {
        // ---- emb stats: 2 nodes per block, 128 threads each ----
        int n = (blockIdx.x - NN) * 2 + (t >> 7);
        int d = t & 127;
        float e = emb[n * DD + d];
        float pi = e * att_em_i[d];
        float pj = e * att_em_j[d];
        double pn = (double)e * (double)e;
        for (int off = 32; off; off >>= 1) {
            pi += __shfl_down(pi, off);
            pj += __shfl_down(pj, off);
            pn += __shfl_down(pn, off);
        }
        __shared__ float ri[4], rj[4];
        __shared__ double rn[4];
        if (lane == 0) { ri[wid] = pi; rj[wid] = pj; rn[wid] = pn; }
        __syncthreads();
        if ((t & 127) == 0) {
            int w0 = (t >> 7) * 2;        // 0 for node0 (wids 0,1), 2 for node1 (wids 2,3)
            eemi[n] = ri[w0] + ri[w0 + 1];
            eemj[n] = rj[w0] + rj[w0 + 1];
            nrm2[n] = rn[w0] + rn[w0 + 1];
        }
    }
}

// ---------------- Kernel C: split-K covariance, UPPER-TRIANGLE tiles only ------
// 10 of 16 64x64 tiles (cov symmetric). cov8 body otherwise: fp32 LDS pad-68,
// 4x4 fp64 acc, short-lived staging regs (no spill; cov3/4 post-mortem).
__global__ __launch_bounds__(256) void k_cov9(const float* __restrict__ data,
                                              double* __restrict__ covp, int bpc) {
    // decode upper-triangle tile index -> (bi, bj)
    int rem = blockIdx.x, bi = 0;
    while (rem >= 4 - bi) { rem -= 4 - bi; ++bi; }
    const int i0 = bi * 64;
    const int j0 = (bi + rem) * 64;
    const int bz = blockIdx.y;
    const int t = threadIdx.x;
    const int ti = t >> 4, tj = t & 15;   // both 0..15

    __shared__ float As[64][68];
    __shared__ float Bs[64][68];

    const int b0 = bz * bpc;
    double acc[4][4] = {};

    #pragma unroll 1
    for (int cb = 0; cb < bpc; ++cb) {
        const int b = b0 + cb;
        #pragma unroll
        for (int e = 0; e < 4; ++e) {
            int idx = t + e * 256, row = idx >> 4, q = idx & 15;
            float4 va = ((const float4*)(data + ((size_t)b * NN + i0 + row) * WW))[q];
            float4 vb = ((const float4*)(data + ((size_t)b * NN + j0 + row) * WW))[q];
            *(float4*)&As[row][4 * q] = va;
            *(float4*)&Bs[row][4 * q] = vb;
        }
        __syncthreads();

        #pragma unroll 2
        for (int q = 0; q < 16; ++q) {
            double bd[4][4];
            #pragma unroll
            for (int c = 0; c < 4; ++c) {
                float4 bf = *(const float4*)&Bs[tj + 16 * c][4 * q];
                bd[c][0] = (double)bf.x; bd[c][1] = (double)bf.y;
                bd[c][2] = (double)bf.z; bd[c][3] = (double)bf.w;
            }
            #pragma unroll
            for (int r = 0; r < 4; ++r) {
                float4 af = *(const float4*)&As[ti + 16 * r][4 * q];
                double a0 = (double)af.x, a1 = (double)af.y;
                double a2 = (double)af.z, a3 = (double)af.w;
                #pragma unroll
                for (int c = 0; c < 4; ++c)
                    acc[r][c] += a0 * bd[c][0] + a1 * bd[c][1]
                               + a2 * bd[c][2] + a3 * bd[c][3];
            }
        }
        __syncthreads();
    }

    #pragma unroll
    for (int r = 0; r < 4; ++r)
        #pragma unroll
        for (int c = 0; c < 4; ++c)
            covp[((size_t)bz * NN + i0 + ti + 16 * r) * NN + j0 + tj + 16 * c] = acc[r][c];
}

// ---------------- Kernel C2: reduce upper pairs, subtract mean term, mirror ----------------
__global__ void k_cov_reduce2(const double* __restrict__ covp,
                              const double* __restrict__ mean,
                              double* __restrict__ cov, int split) {
    int idx = blockIdx.x * 256 + threadIdx.x;
    if (idx >= NPAIR) return;
    // triangular decode: Start_i = i*(2N-i+1)/2
    double dn = (double)(2 * NN + 1);
    int i = (int)((dn - sqrt(dn * dn - 8.0 * (double)idx)) * 0.5);
    while ((i + 1) * (2 * NN - i) / 2 <= idx) ++i;
    while (i * (2 * NN - i + 1) / 2 > idx) --i;
    int j = i + (idx - i * (2 * NN - i + 1) / 2);

    double s = 0.0;
    for (int z = 0; z < split; ++z) s += covp[((size_t)z * NN + i) * NN + j];
    s -= (double)LL * mean[i] * mean[j];
    cov[i * NN + j] = s;
    if (i != j) cov[j * NN + i] = s;
}

// ---------------- Kernel D: sim -> fp32, rank-select top-20 (stable desc, jax tie rule) --------
__global__ void k_sim_topk(const float* __restrict__ emb,
                           const double* __restrict__ nrm2,
                           const double* __restrict__ cov,
                           int* __restrict__ topk) {
    int i = blockIdx.x;
    int t = threadIdx.x;                  // 256 threads; thread t owns column j = t
    __shared__ float embI[DD];
    __shared__ float sim[NN];

    if (t < DD) embI[t] = emb[i * DD + t];
    __syncthreads();

    const float4* er = (const float4*)(emb + (size_t)t * DD);
    double dot = 0.0;
    #pragma unroll 8
    for (int d4 = 0; d4 < DD / 4; ++d4) {
        float4 v = er[d4];
        dot += (double)embI[4 * d4 + 0] * (double)v.x
             + (double)embI[4 * d4 + 1] * (double)v.y
             + (double)embI[4 * d4 + 2] * (double)v.z
             + (double)embI[4 * d4 + 3] * (double)v.w;
    }
    double cosv = dot / (sqrt(nrm2[i]) * sqrt(nrm2[t]) + 1e-8);
    double stdi = sqrt(cov[i * NN + i] + 1e-8);
    double stdj = sqrt(cov[t * NN + t] + 1e-8);
    double corrv = cov[i * NN + t] / (stdi * stdj + 1e-8);
    sim[t] = (float)(0.7 * cosv + 0.3 * corrv);
    __syncthreads();

    float my = sim[t];
    int cnt = 0;
    #pragma unroll 8
    for (int u = 0; u < NN; ++u) {
        float s = sim[u];                 // uniform addr -> LDS broadcast
        cnt += (s > my || (s == my && u < t)) ? 1 : 0;
    }
    if (cnt < KK) topk[i * KK + cnt] = t;
}

// ---------------- Kernel E: xl = x @ lin_W, FUSED with per-row att dots (old k_sij) ------------
__global__ __launch_bounds__(256) void k_xl2s(const float* __restrict__ data,
                                              const float* __restrict__ linW,
                                              const float* __restrict__ att_i,
                                              const float* __restrict__ att_j,
                                              const float* __restrict__ eemi,
                                              const float* __restrict__ eemj,
                                              float* __restrict__ xl,
                                              float* __restrict__ sil,
                                              float* __restrict__ sjl) {
    const int r0 = blockIdx.x * 128;
    const int t = threadIdx.x;            // 256 threads
    const int ti = t >> 4, tj = t & 15;
    __shared__ float Xs[128][68];
    __shared__ float Wt[DD][68];

    #pragma unroll
    for (int e = 0; e < 8; ++e) {
        int idx = t + e * 256, row = idx >> 4, q = idx & 15;
        float4 v = ((const float4*)(data + (size_t)(r0 + row) * WW))[q];
        *(float4*)&Xs[row][4 * q] = v;
    }
    #pragma unroll
    for (int e = 0; e < 32; ++e) {
        int idx = t + e * 256;            // idx = k*128 + col
        int k = idx >> 7, col = idx & 127;
        Wt[col][k] = linW[idx];
    }
    __syncthreads();

    float acc[8][8] = {};                 // rows 8*ti+r, cols tj+16*c
    #pragma unroll
    for (int q = 0; q < 16; ++q) {
        float4 wb[8];
        #pragma unroll
        for (int c = 0; c < 8; ++c) wb[c] = *(const float4*)&Wt[tj + 16 * c][4 * q];
        #pragma unroll
        for (int r = 0; r < 8; ++r) {
            float4 xa = *(const float4*)&Xs[8 * ti + r][4 * q];
            #pragma unroll
            for (int c = 0; c < 8; ++c)
                acc[r][c] += xa.x * wb[c].x + xa.y * wb[c].y
                           + xa.z * wb[c].z + xa.w * wb[c].w;
        }
    }
    #pragma unroll
    for (int r = 0; r < 8; ++r)
        #pragma unroll
        for (int c = 0; c < 8; ++c)
            xl[(size_t)(r0 + 8 * ti + r) * DD + tj + 16 * c] = acc[r][c];

    // ---- fused att dots: row v's si/sj from acc (cols tj+16c live in this thread) ----
    float ai[8], aj[8];
    #pragma unroll
    for (int c = 0; c < 8; ++c) { ai[c] = att_i[tj + 16 * c]; aj[c] = att_j[tj + 16 * c]; }
    #pragma unroll
    for (int r = 0; r < 8; ++r) {
        float pi = 0.f, pj = 0.f;
        #pragma unroll
        for (int c = 0; c < 8; ++c) { pi += acc[r][c] * ai[c]; pj += acc[r][c] * aj[c]; }
        #pragma unroll
        for (int m = 8; m; m >>= 1) { pi += __shfl_xor(pi, m); pj += __shfl_xor(pj, m); }
        if (tj == 0) {
            int v = r0 + 8 * ti + r;
            int node = v & (NN - 1);
            sil[v] = pi + eemi[node];
            sjl[v] = pj + eemj[node];
        }
    }
}

// ---------------- Kernel F: fused attention v2 ----------------
__global__ __launch_bounds__(512) void k_attn2(
        const float* __restrict__ xl, const int* __restrict__ topk,
        const float* __restrict__ sil, const float* __restrict__ sjl,
        const float* __restrict__ gnn_bias,
        const float* __restrict__ bn1_g, const float* __restrict__ bn1_b,
        const float* __restrict__ bn2_g, const float* __restrict__ bn2_b,
        const float* __restrict__ emb,
        const float* __restrict__ outW, const float* __restrict__ outb,
        float* __restrict__ out) {
    const int h = blockIdx.x;             // node half: 0 or 1
    const int b = blockIdx.y;             // batch
    const int t = threadIdx.x;            // 512 threads = 8 waves
    const int lane = t & 63, wv = t >> 6;
    const int q = lane & 31, half = lane >> 5;

    __shared__ float xls[NN * DD];        // 128 KB: xl[b]
    __shared__ int2 jwS[128 * KK];        // 20 KB: packed (j, w) per local node

    {
        const float4* src = (const float4*)(xl + (size_t)b * NN * DD);
        float4* dst = (float4*)xls;
        #pragma unroll
        for (int e = 0; e < 16; ++e) dst[t + e * 512] = src[t + e * 512];
    }

    if (t < 128) {
        int i = h * 128 + t;
        float si = sil[b * NN + i];
        int jj[KK]; float aa[KK];
        float amax = -3.4e38f;
        #pragma unroll
        for (int k = 0; k < KK; ++k) {
            int j = topk[i * KK + k];
            jj[k] = j;
            float a = si + sjl[b * NN + j];
            a = a > 0.f ? a : 0.2f * a;   // leaky relu
            aa[k] = a;
            amax = fmaxf(amax, a);
        }
        float den = 0.f;
        #pragma unroll
        for (int k = 0; k < KK; ++k) { float e = expf(aa[k] - amax); aa[k] = e; den += e; }
        float r = 1.f / den;
        #pragma unroll
        for (int k = 0; k < KK; ++k)
            jwS[t * KK + k] = make_int2(jj[k], __float_as_int(aa[k] * r));
    }
    __syncthreads();

    const float rbnd = 1.0f / sqrtf(1.0f + 1e-5f);
    const float4 gb = ((const float4*)gnn_bias)[q];
    const float4 g1 = ((const float4*)bn1_g)[q];
    const float4 b1 = ((const float4*)bn1_b)[q];
    const float4 g2 = ((const float4*)bn2_g)[q];
    const float4 b2 = ((const float4*)bn2_b)[q];
    const float4 ow = ((const float4*)outW)[q];
    const float ob0 = outb[0];

    for (int n = 0; n < 8; ++n) {
        int il = wv * 16 + 2 * n + half;  // local node 0..127
        int i  = h * 128 + il;

        float ax = 0.f, ay = 0.f, az = 0.f, aw = 0.f;
        #pragma unroll
        for (int k = 0; k < KK; ++k) {
            int2 p = jwS[il * KK + k];
            float w = __int_as_float(p.y);
            float4 xv = *(const float4*)&xls[p.x * DD + 4 * q];
            ax += w * xv.x; ay += w * xv.y; az += w * xv.z; aw += w * xv.w;
        }

        float4 em = *(const float4*)&emb[(size_t)i * DD + 4 * q];
        float o0 = (ax + gb.x) * rbnd * g1.x + b1.x; o0 = fmaxf(o0, 0.f);
        float o1 = (ay + gb.y) * rbnd * g1.y + b1.y; o1 = fmaxf(o1, 0.f);
        float o2 = (az + gb.z) * rbnd * g1.z + b1.z; o2 = fmaxf(o2, 0.f);
        float o3 = (aw + gb.w) * rbnd * g1.w + b1.w; o3 = fmaxf(o3, 0.f);
        float h0 = o0 * em.x * rbnd * g2.x + b2.x; h0 = fmaxf(h0, 0.f);
        float h1 = o1 * em.y * rbnd * g2.y + b2.y; h1 = fmaxf(h1, 0.f);
        float h2 = o2 * em.z * rbnd * g2.z + b2.z; h2 = fmaxf(h2, 0.f);
        float h3 = o3 * em.w * rbnd * g2.w + b2.w; h3 = fmaxf(h3, 0.f);

        float p4 = h0 * ow.x + h1 * ow.y + h2 * ow.z + h3 * ow.w;
        #pragma unroll
        for (int off = 16; off; off >>= 1) p4 += __shfl_xor(p4, off);
        if (q == 0) out[b * NN + i] = p4 + ob0;
    }
}

extern "C" void kernel_launch(void* const* d_in, const int* in_sizes, int n_in,
                              void* d_out, int out_size, void* d_ws, size_t ws_size,
                              hipStream_t stream) {
    const float* data     = (const float*)d_in[0];
    // d_in[1] = org_edge_index (unused, as in reference)
    const float* emb      = (const float*)d_in[2];
    const float* linW     = (const float*)d_in[3];
    const float* att_i    = (const float*)d_in[4];
    const float* att_j    = (const float*)d_in[5];
    const float* att_em_i = (const float*)d_in[6];
    const float* att_em_j = (const float*)d_in[7];
    const float* gnn_bias = (const float*)d_in[8];
    const float* bn1_g    = (const float*)d_in[9];
    const float* bn1_b    = (const float*)d_in[10];
    const float* bn2_g    = (const float*)d_in[11];
    const float* bn2_b    = (const float*)d_in[12];
    const float* outW     = (const float*)d_in[13];
    const float* outb     = (const float*)d_in[14];
    float* out = (float*)d_out;

    char* ws = (char*)d_ws;
    double* mean  = (double*)(ws + 0);                       // 2 KB
    double* nrm2  = (double*)(ws + 2048);                    // 2 KB
    float*  eemi  = (float*)(ws + 4096);                     // 1 KB
    float*  eemj  = (float*)(ws + 5120);                     // 1 KB
    int*    topk  = (int*)(ws + 8192);                       // 20 KB
    double* cov   = (double*)(ws + 32768);                   // 512 KB
    // covp at +1MB: split*256*256*8 B. xl (16 MB) aliases covp (dead after reduce2).
    double* covp  = (double*)(ws + (1 << 20));
    float*  xl    = (float*)(ws + (1 << 20));
    // sil/sjl reuse the cov region (cov dead after k_sim_topk; xl2s runs after topk).
    float*  sil   = (float*)(ws + 32768);
    float*  sjl   = (float*)(ws + 32768 + 131072);

    int split = (ws_size >= (size_t)(1 << 20) + (size_t)64 * NN * NN * 8 + (1 << 16)) ? 64 : 32;
    int bpc = BB / split;

    k_pre<<<NN + NN / 2, 256, 0, stream>>>(data, emb, att_em_i, att_em_j,
                                           mean, eemi, eemj, nrm2);
    dim3 gc(10, split);
    k_cov9<<<gc, 256, 0, stream>>>(data, covp, bpc);
    k_cov_reduce2<<<(NPAIR + 255) / 256, 256, 0, stream>>>(covp, mean, cov, split);
    k_sim_topk<<<NN, 256, 0, stream>>>(emb, nrm2, cov, topk);
    k_xl2s<<<(BB * NN) / 128, 256, 0, stream>>>(data, linW, att_i, att_j, eemi, eemj,
                                                xl, sil, sjl);
    dim3 ga(2, BB);
    k_attn2<<<ga, 512, 0, stream>>>(xl, topk, sil, sjl, gnn_bias,
                                    bn1_g, bn1_b, bn2_g, bn2_b, emb, outW, outb, out);
}

// Round 11
// 99.198 us; speedup vs baseline: 1.1831x; 1.0820x over previous
//
#include <hip/hip_runtime.h>
#include <math.h>

#define BB 128
#define NN 256
#define WW 64
#define DD 128
#define KK 20
#define LL (BB*WW)   // 8192
#define NPAIR (NN*(NN+1)/2)   // 32896 upper-triangle pairs

// ---------------- Kernel C+A fused: covariance tiles (blocks < 20*split) + pre (rest) ----------
// cov path: 20 upper-triangle 64x32 tiles, 256 threads, 4x2 fp64 acc/thread, 26 KB LDS
// -> 1280 blocks at split=64 = 5 blocks/CU uniform (cov9 post-mortem: 640 blocks = 2.5/CU
//    non-uniform was the limiter). pre path: per-node means + emb stats (k_pre body).
__global__ __launch_bounds__(256) void k_covpre(const float* __restrict__ data,
                                                const float* __restrict__ emb,
                                                const float* __restrict__ att_em_i,
                                                const float* __restrict__ att_em_j,
                                                double* __restrict__ covp,
                                                double* __restrict__ mean,
                                                float* __restrict__ eemi,
                                                float* __restrict__ eemj,
                                                double* __restrict__ nrm2,
                                                int split, int bpc) {
    const int t = threadIdx.x;            // 256 threads
    const int ncov = 20 * split;

    if ((int)blockIdx.x >= ncov) {
        // ---------------- pre path ----------------
        const int pb = blockIdx.x - ncov; // 0..383
        const int lane = t & 63, wid = t >> 6;
        if (pb < NN) {
            int n = pb;
            double s = 0.0;
            for (int c = 0; c < LL / 256; ++c) {
                int l = t + c * 256;
                int b = l >> 6, w = l & 63;
                s += (double)data[(b * NN + n) * WW + w];
            }
            for (int off = 32; off; off >>= 1) s += __shfl_down(s, off);
            __shared__ double redm[4];
            if (lane == 0) redm[wid] = s;
            __syncthreads();
            if (t == 0) mean[n] = (redm[0] + redm[1] + redm[2] + redm[3]) / (double)LL;
        } else {
            int n = (pb - NN) * 2 + (t >> 7);
            int d = t & 127;
            float e = emb[n * DD + d];
            float pi = e * att_em_i[d];
            float pj = e * att_em_j[d];
            double pn = (double)e * (double)e;
            for (int off = 32; off; off >>= 1) {
                pi += __shfl_down(pi, off);
                pj += __shfl_down(pj, off);
                pn += __shfl_down(pn, off);
            }
            __shared__ float ri[4], rj[4];
            __shared__ double rn[4];
            if (lane == 0) { ri[wid] = pi; rj[wid] = pj; rn[wid] = pn; }
            __syncthreads();
            if ((t & 127) == 0) {
                int w0 = (t >> 7) * 2;
                eemi[n] = ri[w0] + ri[w0 + 1];
                eemj[n] = rj[w0] + rj[w0 + 1];
                nrm2[n] = rn[w0] + rn[w0 + 1];
            }
        }
        return;
    }

    // ---------------- cov path ----------------
    const int tile = blockIdx.x % 20;
    const int bz = blockIdx.x / 20;
    // decode: bi in 0..3 (64-row blocks), bj32 in 2bi..7 (32-col blocks)
    int rem = tile, bi = 0;
    while (rem >= 8 - 2 * bi) { rem -= 8 - 2 * bi; ++bi; }
    const int i0 = bi * 64;
    const int j0 = (2 * bi + rem) * 32;

    const int ti = t >> 4, tj = t & 15;   // ti 0..15, tj 0..15

    __shared__ float As[64][68];          // 17.4 KB
    __shared__ float Bs[32][68];          // 8.7 KB

    const int b0 = bz * bpc;
    double acc[4][2] = {};

    #pragma unroll 1
    for (int cb = 0; cb < bpc; ++cb) {
        const int b = b0 + cb;
        #pragma unroll
        for (int e = 0; e < 4; ++e) {
            int idx = t + e * 256, row = idx >> 4, q = idx & 15;
            float4 va = ((const float4*)(data + ((size_t)b * NN + i0 + row) * WW))[q];
            *(float4*)&As[row][4 * q] = va;
        }
        #pragma unroll
        for (int e = 0; e < 2; ++e) {
            int idx = t + e * 256, row = idx >> 4, q = idx & 15;
            float4 vb = ((const float4*)(data + ((size_t)b * NN + j0 + row) * WW))[q];
            *(float4*)&Bs[row][4 * q] = vb;
        }
        __syncthreads();

        #pragma unroll 2
        for (int q = 0; q < 16; ++q) {
            double bd[2][4];
            #pragma unroll
            for (int c = 0; c < 2; ++c) {
                float4 bf = *(const float4*)&Bs[tj + 16 * c][4 * q];
                bd[c][0] = (double)bf.x; bd[c][1] = (double)bf.y;
                bd[c][2] = (double)bf.z; bd[c][3] = (double)bf.w;
            }
            #pragma unroll
            for (int r = 0; r < 4; ++r) {
                float4 af = *(const float4*)&As[ti + 16 * r][4 * q];
                double a0 = (double)af.x, a1 = (double)af.y;
                double a2 = (double)af.z, a3 = (double)af.w;
                #pragma unroll
                for (int c = 0; c < 2; ++c)
                    acc[r][c] += a0 * bd[c][0] + a1 * bd[c][1]
                               + a2 * bd[c][2] + a3 * bd[c][3];
            }
        }
        __syncthreads();
    }

    #pragma unroll
    for (int r = 0; r < 4; ++r)
        #pragma unroll
        for (int c = 0; c < 2; ++c)
            covp[((size_t)bz * NN + i0 + ti + 16 * r) * NN + j0 + tj + 16 * c] = acc[r][c];
}

// ---------------- Kernel C2: reduce upper pairs, subtract mean term, mirror ----------------
__global__ void k_cov_reduce2(const double* __restrict__ covp,
                              const double* __restrict__ mean,
                              double* __restrict__ cov, int split) {
    int idx = blockIdx.x * 256 + threadIdx.x;
    if (idx >= NPAIR) return;
    double dn = (double)(2 * NN + 1);
    int i = (int)((dn - sqrt(dn * dn - 8.0 * (double)idx)) * 0.5);
    while ((i + 1) * (2 * NN - i) / 2 <= idx) ++i;
    while (i * (2 * NN - i + 1) / 2 > idx) --i;
    int j = i + (idx - i * (2 * NN - i + 1) / 2);

    double s = 0.0;
    for (int z = 0; z < split; ++z) s += covp[((size_t)z * NN + i) * NN + j];
    s -= (double)LL * mean[i] * mean[j];
    cov[i * NN + j] = s;
    if (i != j) cov[j * NN + i] = s;
}

// ---------------- Kernel D: sim -> fp32, rank-select top-20 (stable desc, jax tie rule) --------
__global__ void k_sim_topk(const float* __restrict__ emb,
                           const double* __restrict__ nrm2,
                           const double* __restrict__ cov,
                           int* __restrict__ topk) {
    int i = blockIdx.x;
    int t = threadIdx.x;                  // 256 threads; thread t owns column j = t
    __shared__ float embI[DD];
    __shared__ float sim[NN];

    if (t < DD) embI[t] = emb[i * DD + t];
    __syncthreads();

    const float4* er = (const float4*)(emb + (size_t)t * DD);
    double dot = 0.0;
    #pragma unroll 8
    for (int d4 = 0; d4 < DD / 4; ++d4) {
        float4 v = er[d4];
        dot += (double)embI[4 * d4 + 0] * (double)v.x
             + (double)embI[4 * d4 + 1] * (double)v.y
             + (double)embI[4 * d4 + 2] * (double)v.z
             + (double)embI[4 * d4 + 3] * (double)v.w;
    }
    double cosv = dot / (sqrt(nrm2[i]) * sqrt(nrm2[t]) + 1e-8);
    double stdi = sqrt(cov[i * NN + i] + 1e-8);
    double stdj = sqrt(cov[t * NN + t] + 1e-8);
    double corrv = cov[i * NN + t] / (stdi * stdj + 1e-8);
    sim[t] = (float)(0.7 * cosv + 0.3 * corrv);
    __syncthreads();

    float my = sim[t];
    int cnt = 0;
    #pragma unroll 8
    for (int u = 0; u < NN; ++u) {
        float s = sim[u];                 // uniform addr -> LDS broadcast
        cnt += (s > my || (s == my && u < t)) ? 1 : 0;
    }
    if (cnt < KK) topk[i * KK + cnt] = t;
}

// ---------------- Kernel E: xl = x @ lin_W, fused with per-row att dots ----------------
__global__ __launch_bounds__(256) void k_xl2s(const float* __restrict__ data,
                                              const float* __restrict__ linW,
                                              const float* __restrict__ att_i,
                                              const float* __restrict__ att_j,
                                              const float* __restrict__ eemi,
                                              const float* __restrict__ eemj,
                                              float* __restrict__ xl,
                                              float* __restrict__ sil,
                                              float* __restrict__ sjl) {
    const int r0 = blockIdx.x * 128;
    const int t = threadIdx.x;            // 256 threads
    const int ti = t >> 4, tj = t & 15;
    __shared__ float Xs[128][68];
    __shared__ float Wt[DD][68];

    #pragma unroll
    for (int e = 0; e < 8; ++e) {
        int idx = t + e * 256, row = idx >> 4, q = idx & 15;
        float4 v = ((const float4*)(data + (size_t)(r0 + row) * WW))[q];
        *(float4*)&Xs[row][4 * q] = v;
    }
    #pragma unroll
    for (int e = 0; e < 32; ++e) {
        int idx = t + e * 256;            // idx = k*128 + col
        int k = idx >> 7, col = idx & 127;
        Wt[col][k] = linW[idx];
    }
    __syncthreads();

    float acc[8][8] = {};                 // rows 8*ti+r, cols tj+16*c
    #pragma unroll
    for (int q = 0; q < 16; ++q) {
        float4 wb[8];
        #pragma unroll
        for (int c = 0; c < 8; ++c) wb[c] = *(const float4*)&Wt[tj + 16 * c][4 * q];
        #pragma unroll
        for (int r = 0; r < 8; ++r) {
            float4 xa = *(const float4*)&Xs[8 * ti + r][4 * q];
            #pragma unroll
            for (int c = 0; c < 8; ++c)
                acc[r][c] += xa.x * wb[c].x + xa.y * wb[c].y
                           + xa.z * wb[c].z + xa.w * wb[c].w;
        }
    }
    #pragma unroll
    for (int r = 0; r < 8; ++r)
        #pragma unroll
        for (int c = 0; c < 8; ++c)
            xl[(size_t)(r0 + 8 * ti + r) * DD + tj + 16 * c] = acc[r][c];

    float ai[8], aj[8];
    #pragma unroll
    for (int c = 0; c < 8; ++c) { ai[c] = att_i[tj + 16 * c]; aj[c] = att_j[tj + 16 * c]; }
    #pragma unroll
    for (int r = 0; r < 8; ++r) {
        float pi = 0.f, pj = 0.f;
        #pragma unroll
        for (int c = 0; c < 8; ++c) { pi += acc[r][c] * ai[c]; pj += acc[r][c] * aj[c]; }
        #pragma unroll
        for (int m = 8; m; m >>= 1) { pi += __shfl_xor(pi, m); pj += __shfl_xor(pj, m); }
        if (tj == 0) {
            int v = r0 + 8 * ti + r;
            int node = v & (NN - 1);
            sil[v] = pi + eemi[node];
            sjl[v] = pj + eemj[node];
        }
    }
}

// ---------------- Kernel F: fused attention v2 ----------------
__global__ __launch_bounds__(512) void k_attn2(
        const float* __restrict__ xl, const int* __restrict__ topk,
        const float* __restrict__ sil, const float* __restrict__ sjl,
        const float* __restrict__ gnn_bias,
        const float* __restrict__ bn1_g, const float* __restrict__ bn1_b,
        const float* __restrict__ bn2_g, const float* __restrict__ bn2_b,
        const float* __restrict__ emb,
        const float* __restrict__ outW, const float* __restrict__ outb,
        float* __restrict__ out) {
    const int h = blockIdx.x;             // node half: 0 or 1
    const int b = blockIdx.y;             // batch
    const int t = threadIdx.x;            // 512 threads = 8 waves
    const int lane = t & 63, wv = t >> 6;
    const int q = lane & 31, half = lane >> 5;

    __shared__ float xls[NN * DD];        // 128 KB: xl[b]
    __shared__ int2 jwS[128 * KK];        // 20 KB

    {
        const float4* src = (const float4*)(xl + (size_t)b * NN * DD);
        float4* dst = (float4*)xls;
        #pragma unroll
        for (int e = 0; e < 16; ++e) dst[t + e * 512] = src[t + e * 512];
    }

    if (t < 128) {
        int i = h * 128 + t;
        float si = sil[b * NN + i];
        int jj[KK]; float aa[KK];
        float amax = -3.4e38f;
        #pragma unroll
        for (int k = 0; k < KK; ++k) {
            int j = topk[i * KK + k];
            jj[k] = j;
            float a = si + sjl[b * NN + j];
            a = a > 0.f ? a : 0.2f * a;   // leaky relu
            aa[k] = a;
            amax = fmaxf(amax, a);
        }
        float den = 0.f;
        #pragma unroll
        for (int k = 0; k < KK; ++k) { float e = expf(aa[k] - amax); aa[k] = e; den += e; }
        float r = 1.f / den;
        #pragma unroll
        for (int k = 0; k < KK; ++k)
            jwS[t * KK + k] = make_int2(jj[k], __float_as_int(aa[k] * r));
    }
    __syncthreads();

    const float rbnd = 1.0f / sqrtf(1.0f + 1e-5f);
    const float4 gb = ((const float4*)gnn_bias)[q];
    const float4 g1 = ((const float4*)bn1_g)[q];
    const float4 b1 = ((const float4*)bn1_b)[q];
    const float4 g2 = ((const float4*)bn2_g)[q];
    const float4 b2 = ((const float4*)bn2_b)[q];
    const float4 ow = ((const float4*)outW)[q];
    const float ob0 = outb[0];

    for (int n = 0; n < 8; ++n) {
        int il = wv * 16 + 2 * n + half;  // local node 0..127
        int i  = h * 128 + il;

        float ax = 0.f, ay = 0.f, az = 0.f, aw = 0.f;
        #pragma unroll
        for (int k = 0; k < KK; ++k) {
            int2 p = jwS[il * KK + k];
            float w = __int_as_float(p.y);
            float4 xv = *(const float4*)&xls[p.x * DD + 4 * q];
            ax += w * xv.x; ay += w * xv.y; az += w * xv.z; aw += w * xv.w;
        }

        float4 em = *(const float4*)&emb[(size_t)i * DD + 4 * q];
        float o0 = (ax + gb.x) * rbnd * g1.x + b1.x; o0 = fmaxf(o0, 0.f);
        float o1 = (ay + gb.y) * rbnd * g1.y + b1.y; o1 = fmaxf(o1, 0.f);
        float o2 = (az + gb.z) * rbnd * g1.z + b1.z; o2 = fmaxf(o2, 0.f);
        float o3 = (aw + gb.w) * rbnd * g1.w + b1.w; o3 = fmaxf(o3, 0.f);
        float h0 = o0 * em.x * rbnd * g2.x + b2.x; h0 = fmaxf(h0, 0.f);
        float h1 = o1 * em.y * rbnd * g2.y + b2.y; h1 = fmaxf(h1, 0.f);
        float h2 = o2 * em.z * rbnd * g2.z + b2.z; h2 = fmaxf(h2, 0.f);
        float h3 = o3 * em.w * rbnd * g2.w + b2.w; h3 = fmaxf(h3, 0.f);

        float p4 = h0 * ow.x + h1 * ow.y + h2 * ow.z + h3 * ow.w;
        #pragma unroll
        for (int off = 16; off; off >>= 1) p4 += __shfl_xor(p4, off);
        if (q == 0) out[b * NN + i] = p4 + ob0;
    }
}

extern "C" void kernel_launch(void* const* d_in, const int* in_sizes, int n_in,
                              void* d_out, int out_size, void* d_ws, size_t ws_size,
                              hipStream_t stream) {
    const float* data     = (const float*)d_in[0];
    // d_in[1] = org_edge_index (unused, as in reference)
    const float* emb      = (const float*)d_in[2];
    const float* linW     = (const float*)d_in[3];
    const float* att_i    = (const float*)d_in[4];
    const float* att_j    = (const float*)d_in[5];
    const float* att_em_i = (const float*)d_in[6];
    const float* att_em_j = (const float*)d_in[7];
    const float* gnn_bias = (const float*)d_in[8];
    const float* bn1_g    = (const float*)d_in[9];
    const float* bn1_b    = (const float*)d_in[10];
    const float* bn2_g    = (const float*)d_in[11];
    const float* bn2_b    = (const float*)d_in[12];
    const float* outW     = (const float*)d_in[13];
    const float* outb     = (const float*)d_in[14];
    float* out = (float*)d_out;

    char* ws = (char*)d_ws;
    double* mean  = (double*)(ws + 0);                       // 2 KB
    double* nrm2  = (double*)(ws + 2048);                    // 2 KB
    float*  eemi  = (float*)(ws + 4096);                     // 1 KB
    float*  eemj  = (float*)(ws + 5120);                     // 1 KB
    int*    topk  = (int*)(ws + 8192);                       // 20 KB
    double* cov   = (double*)(ws + 32768);                   // 512 KB
    // covp at +1MB: split*256*256*8 B (33.5 MB at split=64). xl (16 MB) aliases covp
    // (covp dead after k_cov_reduce2, stream-ordered).
    double* covp  = (double*)(ws + (1 << 20));
    float*  xl    = (float*)(ws + (1 << 20));
    // sil/sjl reuse the cov region (cov dead after k_sim_topk; xl2s runs after topk).
    float*  sil   = (float*)(ws + 32768);
    float*  sjl   = (float*)(ws + 32768 + 131072);

    int split = (ws_size >= (size_t)(1 << 20) + (size_t)64 * NN * NN * 8 + (1 << 16)) ? 64 : 32;
    int bpc = BB / split;

    k_covpre<<<20 * split + NN + NN / 2, 256, 0, stream>>>(
        data, emb, att_em_i, att_em_j, covp, mean, eemi, eemj, nrm2, split, bpc);
    k_cov_reduce2<<<(NPAIR + 255) / 256, 256, 0, stream>>>(covp, mean, cov, split);
    k_sim_topk<<<NN, 256, 0, stream>>>(emb, nrm2, cov, topk);
    k_xl2s<<<(BB * NN) / 128, 256, 0, stream>>>(data, linW, att_i, att_j, eemi, eemj,
                                                xl, sil, sjl);
    dim3 ga(2, BB);
    k_attn2<<<ga, 512, 0, stream>>>(xl, topk, sil, sjl, gnn_bias,
                                    bn1_g, bn1_b, bn2_g, bn2_b, emb, outW, outb, out);
}

// Round 12
// 72.476 us; speedup vs baseline: 1.6193x; 1.3687x over previous
//
#include <hip/hip_runtime.h>
#include <math.h>

#define BB 128
#define NN 256
#define WW 64
#define DD 128
#define KK 20
#define LL (BB*WW)   // 8192
#define NPAIR (NN*(NN+1)/2)   // 32896 upper-triangle pairs

// ---------------- Kernel 1: cov tiles (fp32 chunk partials) + means/emb-stats ----------------
// cov path: 20 upper-triangle 64x32 tiles x split chunks. Inner loop pure fp32 (acc fp32,
// no cvt): per-partial = bpc*64 products in fp32 (error ~7e-6 abs; corr error ~1e-9 after
// the fp64 reduce across partials - 10^4 below the fp32 reference's own noise).
__global__ __launch_bounds__(256) void k_covpre(const float* __restrict__ data,
                                                const float* __restrict__ emb,
                                                const float* __restrict__ att_em_i,
                                                const float* __restrict__ att_em_j,
                                                float* __restrict__ covp,
                                                double* __restrict__ mean,
                                                float* __restrict__ eemi,
                                                float* __restrict__ eemj,
                                                double* __restrict__ nrm2,
                                                int split, int bpc) {
    const int t = threadIdx.x;            // 256 threads
    const int ncov = 20 * split;

    if ((int)blockIdx.x >= ncov) {
        // ---------------- pre path ----------------
        const int pb = blockIdx.x - ncov; // 0..383
        const int lane = t & 63, wid = t >> 6;
        if (pb < NN) {
            int n = pb;
            double s = 0.0;
            for (int c = 0; c < LL / 256; ++c) {
                int l = t + c * 256;
                int b = l >> 6, w = l & 63;
                s += (double)data[(b * NN + n) * WW + w];
            }
            for (int off = 32; off; off >>= 1) s += __shfl_down(s, off);
            __shared__ double redm[4];
            if (lane == 0) redm[wid] = s;
            __syncthreads();
            if (t == 0) mean[n] = (redm[0] + redm[1] + redm[2] + redm[3]) / (double)LL;
        } else {
            int n = (pb - NN) * 2 + (t >> 7);
            int d = t & 127;
            float e = emb[n * DD + d];
            float pi = e * att_em_i[d];
            float pj = e * att_em_j[d];
            double pn = (double)e * (double)e;
            for (int off = 32; off; off >>= 1) {
                pi += __shfl_down(pi, off);
                pj += __shfl_down(pj, off);
                pn += __shfl_down(pn, off);
            }
            __shared__ float ri[4], rj[4];
            __shared__ double rn[4];
            if (lane == 0) { ri[wid] = pi; rj[wid] = pj; rn[wid] = pn; }
            __syncthreads();
            if ((t & 127) == 0) {
                int w0 = (t >> 7) * 2;
                eemi[n] = ri[w0] + ri[w0 + 1];
                eemj[n] = rj[w0] + rj[w0 + 1];
                nrm2[n] = rn[w0] + rn[w0 + 1];
            }
        }
        return;
    }

    // ---------------- cov path (fp32) ----------------
    const int tile = blockIdx.x % 20;
    const int bz = blockIdx.x / 20;
    int rem = tile, bi = 0;
    while (rem >= 8 - 2 * bi) { rem -= 8 - 2 * bi; ++bi; }
    const int i0 = bi * 64;
    const int j0 = (2 * bi + rem) * 32;

    const int ti = t >> 4, tj = t & 15;   // ti 0..15, tj 0..15

    __shared__ float As[64][68];
    __shared__ float Bs[32][68];

    const int b0 = bz * bpc;
    float acc[4][2] = {};

    #pragma unroll 1
    for (int cb = 0; cb < bpc; ++cb) {
        const int b = b0 + cb;
        #pragma unroll
        for (int e = 0; e < 4; ++e) {
            int idx = t + e * 256, row = idx >> 4, q = idx & 15;
            float4 va = ((const float4*)(data + ((size_t)b * NN + i0 + row) * WW))[q];
            *(float4*)&As[row][4 * q] = va;
        }
        #pragma unroll
        for (int e = 0; e < 2; ++e) {
            int idx = t + e * 256, row = idx >> 4, q = idx & 15;
            float4 vb = ((const float4*)(data + ((size_t)b * NN + j0 + row) * WW))[q];
            *(float4*)&Bs[row][4 * q] = vb;
        }
        __syncthreads();

        #pragma unroll 4
        for (int q = 0; q < 16; ++q) {
            float4 b0v = *(const float4*)&Bs[tj][4 * q];
            float4 b1v = *(const float4*)&Bs[tj + 16][4 * q];
            #pragma unroll
            for (int r = 0; r < 4; ++r) {
                float4 af = *(const float4*)&As[ti + 16 * r][4 * q];
                acc[r][0] += af.x * b0v.x + af.y * b0v.y + af.z * b0v.z + af.w * b0v.w;
                acc[r][1] += af.x * b1v.x + af.y * b1v.y + af.z * b1v.z + af.w * b1v.w;
            }
        }
        __syncthreads();
    }

    #pragma unroll
    for (int r = 0; r < 4; ++r)
        #pragma unroll
        for (int c = 0; c < 2; ++c)
            covp[((size_t)bz * NN + i0 + ti + 16 * r) * NN + j0 + tj + 16 * c] = acc[r][c];
}

// ---------------- Kernel 2: FUSED {xl = x@lin_W + att dots} (blocks 0..255)
//                        and {cov reduce: fp64 sum of fp32 partials + mirror} (blocks 256..384)
__global__ __launch_bounds__(256) void k_phase2(const float* __restrict__ covp,
                                                const double* __restrict__ mean,
                                                double* __restrict__ cov,
                                                const float* __restrict__ data,
                                                const float* __restrict__ linW,
                                                const float* __restrict__ att_i,
                                                const float* __restrict__ att_j,
                                                const float* __restrict__ eemi,
                                                const float* __restrict__ eemj,
                                                float* __restrict__ xl,
                                                float* __restrict__ sil,
                                                float* __restrict__ sjl,
                                                int split) {
    __shared__ float Xs[128][68];
    __shared__ float Wt[DD][68];
    const int t = threadIdx.x;            // 256 threads

    if (blockIdx.x >= NN) {
        // ---------------- cov reduce path ----------------
        int idx = (blockIdx.x - NN) * 256 + t;
        if (idx >= NPAIR) return;
        double dn = (double)(2 * NN + 1);
        int i = (int)((dn - sqrt(dn * dn - 8.0 * (double)idx)) * 0.5);
        while ((i + 1) * (2 * NN - i) / 2 <= idx) ++i;
        while (i * (2 * NN - i + 1) / 2 > idx) --i;
        int j = i + (idx - i * (2 * NN - i + 1) / 2);

        double s = 0.0;
        for (int z = 0; z < split; ++z) s += (double)covp[((size_t)z * NN + i) * NN + j];
        s -= (double)LL * mean[i] * mean[j];
        cov[i * NN + j] = s;
        if (i != j) cov[j * NN + i] = s;
        return;
    }

    // ---------------- xl + att-dots path ----------------
    const int r0 = blockIdx.x * 128;
    const int ti = t >> 4, tj = t & 15;

    #pragma unroll
    for (int e = 0; e < 8; ++e) {
        int idx = t + e * 256, row = idx >> 4, q = idx & 15;
        float4 v = ((const float4*)(data + (size_t)(r0 + row) * WW))[q];
        *(float4*)&Xs[row][4 * q] = v;
    }
    #pragma unroll
    for (int e = 0; e < 32; ++e) {
        int idx = t + e * 256;            // idx = k*128 + col
        int k = idx >> 7, col = idx & 127;
        Wt[col][k] = linW[idx];
    }
    __syncthreads();

    float acc[8][8] = {};                 // rows 8*ti+r, cols tj+16*c
    #pragma unroll
    for (int q = 0; q < 16; ++q) {
        float4 wb[8];
        #pragma unroll
        for (int c = 0; c < 8; ++c) wb[c] = *(const float4*)&Wt[tj + 16 * c][4 * q];
        #pragma unroll
        for (int r = 0; r < 8; ++r) {
            float4 xa = *(const float4*)&Xs[8 * ti + r][4 * q];
            #pragma unroll
            for (int c = 0; c < 8; ++c)
                acc[r][c] += xa.x * wb[c].x + xa.y * wb[c].y
                           + xa.z * wb[c].z + xa.w * wb[c].w;
        }
    }
    #pragma unroll
    for (int r = 0; r < 8; ++r)
        #pragma unroll
        for (int c = 0; c < 8; ++c)
            xl[(size_t)(r0 + 8 * ti + r) * DD + tj + 16 * c] = acc[r][c];

    float ai[8], aj[8];
    #pragma unroll
    for (int c = 0; c < 8; ++c) { ai[c] = att_i[tj + 16 * c]; aj[c] = att_j[tj + 16 * c]; }
    #pragma unroll
    for (int r = 0; r < 8; ++r) {
        float pi = 0.f, pj = 0.f;
        #pragma unroll
        for (int c = 0; c < 8; ++c) { pi += acc[r][c] * ai[c]; pj += acc[r][c] * aj[c]; }
        #pragma unroll
        for (int m = 8; m; m >>= 1) { pi += __shfl_xor(pi, m); pj += __shfl_xor(pj, m); }
        if (tj == 0) {
            int v = r0 + 8 * ti + r;
            int node = v & (NN - 1);
            sil[v] = pi + eemi[node];
            sjl[v] = pj + eemj[node];
        }
    }
}

// ---------------- Kernel 3: sim -> fp32, rank-select top-20 (stable desc, jax tie rule) --------
__global__ void k_sim_topk(const float* __restrict__ emb,
                           const double* __restrict__ nrm2,
                           const double* __restrict__ cov,
                           int* __restrict__ topk) {
    int i = blockIdx.x;
    int t = threadIdx.x;                  // 256 threads; thread t owns column j = t
    __shared__ float embI[DD];
    __shared__ float sim[NN];

    if (t < DD) embI[t] = emb[i * DD + t];
    __syncthreads();

    const float4* er = (const float4*)(emb + (size_t)t * DD);
    double dot = 0.0;
    #pragma unroll 8
    for (int d4 = 0; d4 < DD / 4; ++d4) {
        float4 v = er[d4];
        dot += (double)embI[4 * d4 + 0] * (double)v.x
             + (double)embI[4 * d4 + 1] * (double)v.y
             + (double)embI[4 * d4 + 2] * (double)v.z
             + (double)embI[4 * d4 + 3] * (double)v.w;
    }
    double cosv = dot / (sqrt(nrm2[i]) * sqrt(nrm2[t]) + 1e-8);
    double stdi = sqrt(cov[i * NN + i] + 1e-8);
    double stdj = sqrt(cov[t * NN + t] + 1e-8);
    double corrv = cov[i * NN + t] / (stdi * stdj + 1e-8);
    sim[t] = (float)(0.7 * cosv + 0.3 * corrv);
    __syncthreads();

    float my = sim[t];
    int cnt = 0;
    #pragma unroll 8
    for (int u = 0; u < NN; ++u) {
        float s = sim[u];                 // uniform addr -> LDS broadcast
        cnt += (s > my || (s == my && u < t)) ? 1 : 0;
    }
    if (cnt < KK) topk[i * KK + cnt] = t;
}

// ---------------- Kernel 4: fused attention ----------------
__global__ __launch_bounds__(512) void k_attn2(
        const float* __restrict__ xl, const int* __restrict__ topk,
        const float* __restrict__ sil, const float* __restrict__ sjl,
        const float* __restrict__ gnn_bias,
        const float* __restrict__ bn1_g, const float* __restrict__ bn1_b,
        const float* __restrict__ bn2_g, const float* __restrict__ bn2_b,
        const float* __restrict__ emb,
        const float* __restrict__ outW, const float* __restrict__ outb,
        float* __restrict__ out) {
    const int h = blockIdx.x;             // node half: 0 or 1
    const int b = blockIdx.y;             // batch
    const int t = threadIdx.x;            // 512 threads = 8 waves
    const int lane = t & 63, wv = t >> 6;
    const int q = lane & 31, half = lane >> 5;

    __shared__ float xls[NN * DD];        // 128 KB: xl[b]
    __shared__ int2 jwS[128 * KK];        // 20 KB

    {
        const float4* src = (const float4*)(xl + (size_t)b * NN * DD);
        float4* dst = (float4*)xls;
        #pragma unroll
        for (int e = 0; e < 16; ++e) dst[t + e * 512] = src[t + e * 512];
    }

    if (t < 128) {
        int i = h * 128 + t;
        float si = sil[b * NN + i];
        int jj[KK]; float aa[KK];
        float amax = -3.4e38f;
        #pragma unroll
        for (int k = 0; k < KK; ++k) {
            int j = topk[i * KK + k];
            jj[k] = j;
            float a = si + sjl[b * NN + j];
            a = a > 0.f ? a : 0.2f * a;   // leaky relu
            aa[k] = a;
            amax = fmaxf(amax, a);
        }
        float den = 0.f;
        #pragma unroll
        for (int k = 0; k < KK; ++k) { float e = expf(aa[k] - amax); aa[k] = e; den += e; }
        float r = 1.f / den;
        #pragma unroll
        for (int k = 0; k < KK; ++k)
            jwS[t * KK + k] = make_int2(jj[k], __float_as_int(aa[k] * r));
    }
    __syncthreads();

    const float rbnd = 1.0f / sqrtf(1.0f + 1e-5f);
    const float4 gb = ((const float4*)gnn_bias)[q];
    const float4 g1 = ((const float4*)bn1_g)[q];
    const float4 b1 = ((const float4*)bn1_b)[q];
    const float4 g2 = ((const float4*)bn2_g)[q];
    const float4 b2 = ((const float4*)bn2_b)[q];
    const float4 ow = ((const float4*)outW)[q];
    const float ob0 = outb[0];

    for (int n = 0; n < 8; ++n) {
        int il = wv * 16 + 2 * n + half;  // local node 0..127
        int i  = h * 128 + il;

        float ax = 0.f, ay = 0.f, az = 0.f, aw = 0.f;
        #pragma unroll
        for (int k = 0; k < KK; ++k) {
            int2 p = jwS[il * KK + k];
            float w = __int_as_float(p.y);
            float4 xv = *(const float4*)&xls[p.x * DD + 4 * q];
            ax += w * xv.x; ay += w * xv.y; az += w * xv.z; aw += w * xv.w;
        }

        float4 em = *(const float4*)&emb[(size_t)i * DD + 4 * q];
        float o0 = (ax + gb.x) * rbnd * g1.x + b1.x; o0 = fmaxf(o0, 0.f);
        float o1 = (ay + gb.y) * rbnd * g1.y + b1.y; o1 = fmaxf(o1, 0.f);
        float o2 = (az + gb.z) * rbnd * g1.z + b1.z; o2 = fmaxf(o2, 0.f);
        float o3 = (aw + gb.w) * rbnd * g1.w + b1.w; o3 = fmaxf(o3, 0.f);
        float h0 = o0 * em.x * rbnd * g2.x + b2.x; h0 = fmaxf(h0, 0.f);
        float h1 = o1 * em.y * rbnd * g2.y + b2.y; h1 = fmaxf(h1, 0.f);
        float h2 = o2 * em.z * rbnd * g2.z + b2.z; h2 = fmaxf(h2, 0.f);
        float h3 = o3 * em.w * rbnd * g2.w + b2.w; h3 = fmaxf(h3, 0.f);

        float p4 = h0 * ow.x + h1 * ow.y + h2 * ow.z + h3 * ow.w;
        #pragma unroll
        for (int off = 16; off; off >>= 1) p4 += __shfl_xor(p4, off);
        if (q == 0) out[b * NN + i] = p4 + ob0;
    }
}

extern "C" void kernel_launch(void* const* d_in, const int* in_sizes, int n_in,
                              void* d_out, int out_size, void* d_ws, size_t ws_size,
                              hipStream_t stream) {
    const float* data     = (const float*)d_in[0];
    // d_in[1] = org_edge_index (unused, as in reference)
    const float* emb      = (const float*)d_in[2];
    const float* linW     = (const float*)d_in[3];
    const float* att_i    = (const float*)d_in[4];
    const float* att_j    = (const float*)d_in[5];
    const float* att_em_i = (const float*)d_in[6];
    const float* att_em_j = (const float*)d_in[7];
    const float* gnn_bias = (const float*)d_in[8];
    const float* bn1_g    = (const float*)d_in[9];
    const float* bn1_b    = (const float*)d_in[10];
    const float* bn2_g    = (const float*)d_in[11];
    const float* bn2_b    = (const float*)d_in[12];
    const float* outW     = (const float*)d_in[13];
    const float* outb     = (const float*)d_in[14];
    float* out = (float*)d_out;

    // DISJOINT layout (phase2 runs reduce and xl2s concurrently -> no aliasing):
    char* ws = (char*)d_ws;
    double* mean  = (double*)(ws + 0);                       // 2 KB
    double* nrm2  = (double*)(ws + 2048);                    // 2 KB
    float*  eemi  = (float*)(ws + 4096);                     // 1 KB
    float*  eemj  = (float*)(ws + 5120);                     // 1 KB
    int*    topk  = (int*)(ws + 8192);                       // 20 KB
    double* cov   = (double*)(ws + 32768);                   // 512 KB
    float*  covp  = (float*)(ws + (1 << 20));                // split*256KB (16.8 MB @64)
    float*  sil   = (float*)(ws + (30 << 20));               // 128 KB
    float*  sjl   = (float*)(ws + (30 << 20) + (128 << 10)); // 128 KB
    float*  xl    = (float*)(ws + (32 << 20));               // 16 MB

    int split = (ws_size >= (size_t)(48 << 20) + (1 << 20)) ? 64 : 32;
    int bpc = BB / split;

    k_covpre<<<20 * split + NN + NN / 2, 256, 0, stream>>>(
        data, emb, att_em_i, att_em_j, covp, mean, eemi, eemj, nrm2, split, bpc);
    k_phase2<<<NN + (NPAIR + 255) / 256, 256, 0, stream>>>(
        covp, mean, cov, data, linW, att_i, att_j, eemi, eemj, xl, sil, sjl, split);
    k_sim_topk<<<NN, 256, 0, stream>>>(emb, nrm2, cov, topk);
    dim3 ga(2, BB);
    k_attn2<<<ga, 512, 0, stream>>>(xl, topk, sil, sjl, gnn_bias,
                                    bn1_g, bn1_b, bn2_g, bn2_b, emb, outW, outb, out);
}